// Round 5
// baseline (200.511 us; speedup 1.0000x reference)
//
#include <hip/hip_runtime.h>

// PSU LIF: V_t = b*V_{t-1} + x_t ; R_t = b*R_{t-1} + sigmoid(V_t)
// out0 = (V - R - 1 > 0), out1 = V.  x:[16,1024,1024] f32, beta:[1024] f32.
//
// Round-5: float4-across-h. Each thread owns 4 consecutive h and L=16
// timesteps -> every global access is dwordx4 (1KB/wave-instr), 4x fewer
// VMEM instructions than round 3/4's scalar loads (the 7 TB/s harness fills
// use dwordx4; round-4 showed VALU & occupancy are not the limiter).
//   block = 512 thr = 8 f4-groups (32 h) x 64 chunks (L=16); grid = 512.
//   wave  = 8 chunks x 8 groups -> 128B full-line segments per chunk-row.
//   beta is per-thread float4; recurrences elementwise. Carries via LDS
//   (f4 rows, <=63 serial fma4 steps), 2 barriers, same algebra as round 3.
//   VGPR ~108 (arr[16] f4 = 64) under the 128 cap of launch_bounds(512,4)
//   -> no spill (round-2 lesson), 2 blocks/CU, 4 waves/SIMD.
// Traffic optimum: read x 67MB, write V+spike 134MB -> ~31us floor.

#define BB 16
#define TT 1024
#define HH 1024
#define L 16            // timesteps per thread
#define C 64            // chunks per sequence = TT/L
#define G 8             // float4 h-groups per block (32 h)

typedef float f4 __attribute__((ext_vector_type(4)));

__device__ __forceinline__ f4 fma4(f4 a, f4 b, f4 c) {
    f4 r;
#pragma unroll
    for (int k = 0; k < 4; ++k) r[k] = fmaf(a[k], b[k], c[k]);
    return r;
}

__global__ __launch_bounds__(512, 4) void lif_scan(const float* __restrict__ x,
                                                   const float* __restrict__ beta,
                                                   float* __restrict__ out_spike,
                                                   float* __restrict__ out_v) {
    __shared__ f4 lds_v[C][G];              // 8 KB
    __shared__ f4 lds_r[C][G];              // 8 KB

    const int tid = threadIdx.x;
    const int g = tid & (G - 1);            // f4-group within h-tile
    const int c = tid >> 3;                 // chunk 0..63
    const int blk = blockIdx.x;             // 512 blocks
    const int b = blk >> 5;                 // batch (32 h-tiles per batch)
    const int h0 = ((blk & 31) << 5) + (g << 2);  // first of 4 h

    f4 bf = *reinterpret_cast<const f4*>(beta + h0);
#pragma unroll
    for (int k = 0; k < 4; ++k) bf[k] = fminf(fmaxf(bf[k], 0.0f), 1.0f);
    f4 pw = bf;                             // b^L via 4 squarings (L=16)
#pragma unroll
    for (int k = 0; k < 4; ++k) pw *= pw;

    const size_t base = (size_t)b * TT * HH + (size_t)(c * L) * HH + (size_t)h0;
    const f4* __restrict__ xv = reinterpret_cast<const f4*>(x + base);
    f4* __restrict__ vv = reinterpret_cast<f4*>(out_v + base);
    f4* __restrict__ sv = reinterpret_cast<f4*>(out_spike + base);
    const int STRD = HH / 4;                // f4 elements per timestep row

    // ---- load chunk: 16 dwordx4 loads in flight ----
    f4 arr[L];
#pragma unroll
    for (int i = 0; i < L; ++i) arr[i] = __builtin_nontemporal_load(xv + (size_t)i * STRD);

    // ---- phase A: local V scan (zero init) ----
    f4 V = (f4)0.0f;
#pragma unroll
    for (int i = 0; i < L; ++i) {
        V = fma4(bf, V, arr[i]);
        arr[i] = V;
    }
    lds_v[c][g] = V;
    __syncthreads();

    // ---- V carry: Vstart(c) = sum_{j<c} (b^L)^(c-1-j) * vsum_j ----
    f4 Vstart = (f4)0.0f;
    for (int j = 0; j < c; ++j) Vstart = fma4(pw, Vstart, lds_v[j][g]);

    // ---- phase B: exact V, write V, sigmoid, local R scan ----
    f4 vc = Vstart;
    f4 R = (f4)0.0f;
#pragma unroll
    for (int i = 0; i < L; ++i) {
        vc *= bf;                           // b^(i+1) * Vstart
        const f4 vf = arr[i] + vc;
        __builtin_nontemporal_store(vf, vv + (size_t)i * STRD);
        f4 sg;
#pragma unroll
        for (int k = 0; k < 4; ++k) sg[k] = __builtin_amdgcn_rcpf(1.0f + __expf(-vf[k]));
        R = fma4(bf, R, sg);
        arr[i] = vf - R;                    // e_i = V_i - localR_i
    }
    lds_r[c][g] = R;
    __syncthreads();

    // ---- R carry ----
    f4 Rstart = (f4)0.0f;
    for (int j = 0; j < c; ++j) Rstart = fma4(pw, Rstart, lds_r[j][g]);

    // ---- phase C: spike = (e_i - b^(i+1)*Rstart > 1) ----
    f4 rc = Rstart;
#pragma unroll
    for (int i = 0; i < L; ++i) {
        rc *= bf;
        f4 sp;
#pragma unroll
        for (int k = 0; k < 4; ++k) sp[k] = (arr[i][k] - rc[k] > 1.0f) ? 1.0f : 0.0f;
        __builtin_nontemporal_store(sp, sv + (size_t)i * STRD);
    }
}

extern "C" void kernel_launch(void* const* d_in, const int* in_sizes, int n_in,
                              void* d_out, int out_size, void* d_ws, size_t ws_size,
                              hipStream_t stream) {
    const float* x = (const float*)d_in[0];
    const float* beta = (const float*)d_in[1];
    float* out = (float*)d_out;
    float* out_spike = out;                              // [16,1024,1024]
    float* out_v = out + (size_t)BB * TT * HH;           // [16,1024,1024]

    const int grid = (BB * HH) / 32;                     // 512 blocks (32 h each)
    lif_scan<<<grid, 512, 0, stream>>>(x, beta, out_spike, out_v);
}

// Round 6
// 199.472 us; speedup vs baseline: 1.0052x; 1.0052x over previous
//
#include <hip/hip_runtime.h>

// PSU LIF: V_t = b*V_{t-1} + x_t ; R_t = b*R_{t-1} + sigmoid(V_t)
// out0 = (V - R - 1 > 0), out1 = V.  x:[16,1024,1024] f32, beta:[1024] f32.
//
// Round-6: arr-free 3-pass exact rescan to unlock full occupancy.
//   Rounds 3-5 were grid-capped at 16 waves/CU (50%) because arr[16] f4
//   (64 VGPR) forced ~110 VGPR. Dropping the array and re-reading x (pass B,
//   LLC-warm) and V (pass C, L1/L2-warm, same thread wrote it) cuts VGPR to
//   ~50 -> launch_bounds(1024,8) caps 64 VGPR -> 2x1024-thr blocks/CU =
//   32 waves/CU (100%). Each pass rescans the recurrence SEEDED WITH THE
//   EXACT CARRY -> bitwise-sequential f32 numerics (better than r3-r5's
//   carry-add approximation).
//   Geometry: thread = 4 consecutive h (f4) x L=8 timesteps; block = 8
//   f4-groups (32 h, 128B full-line wave segments) x 128 chunks = 1024 thr;
//   grid = 512. Carries: serial fma over LDS chunk sums (<=127 iters, ~1us).
// HBM traffic optimum: read x 67MB, write V+spike 134MB. Extra 134MB of
// re-reads served by LLC.

#define BB 16
#define TT 1024
#define HH 1024
#define L 8             // timesteps per thread
#define C 128           // chunks per sequence = TT/L
#define G 8             // float4 h-groups per block (32 h)

typedef float f4 __attribute__((ext_vector_type(4)));

__device__ __forceinline__ f4 fma4(f4 a, f4 b, f4 c) {
    f4 r;
#pragma unroll
    for (int k = 0; k < 4; ++k) r[k] = fmaf(a[k], b[k], c[k]);
    return r;
}

__global__ __launch_bounds__(1024, 8) void lif_scan(const float* __restrict__ x,
                                                    const float* __restrict__ beta,
                                                    float* __restrict__ out_spike,
                                                    float* __restrict__ out_v) {
    __shared__ f4 lds_v[C][G];              // 16 KB
    __shared__ f4 lds_r[C][G];              // 16 KB

    const int tid = threadIdx.x;
    const int g = tid & (G - 1);            // f4-group within h-tile
    const int c = tid >> 3;                 // chunk 0..127
    const int blk = blockIdx.x;             // 512 blocks
    const int b = blk >> 5;                 // batch (32 h-tiles per batch)
    const int h0 = ((blk & 31) << 5) + (g << 2);  // first of 4 h

    f4 bf = *reinterpret_cast<const f4*>(beta + h0);
#pragma unroll
    for (int k = 0; k < 4; ++k) bf[k] = fminf(fmaxf(bf[k], 0.0f), 1.0f);
    f4 pw = bf;                             // b^L via 3 squarings (L=8)
#pragma unroll
    for (int k = 0; k < 3; ++k) pw *= pw;

    const size_t base = (size_t)b * TT * HH + (size_t)(c * L) * HH + (size_t)h0;
    const f4* __restrict__ xv = reinterpret_cast<const f4*>(x + base);
    f4* __restrict__ vv = reinterpret_cast<f4*>(out_v + base);
    f4* __restrict__ sv = reinterpret_cast<f4*>(out_spike + base);
    const int STRD = HH / 4;                // f4 elements per timestep row

    // ---- pass A: local V chunk-sum only (regular loads -> prime LLC) ----
    f4 V = (f4)0.0f;
#pragma unroll
    for (int i = 0; i < L; ++i) V = fma4(bf, V, xv[(size_t)i * STRD]);
    lds_v[c][g] = V;
    __syncthreads();

    // ---- V carry: Vstart(c) = sum_{j<c} (b^L)^(c-1-j) * vsum_j ----
    f4 Vstart = (f4)0.0f;
    for (int j = 0; j < c; ++j) Vstart = fma4(pw, Vstart, lds_v[j][g]);

    // ---- pass B: exact V rescan seeded with carry; store V; local R sum ----
    V = Vstart;
    f4 R = (f4)0.0f;
#pragma unroll
    for (int i = 0; i < L; ++i) {
        V = fma4(bf, V, xv[(size_t)i * STRD]);   // LLC-warm re-read
        vv[(size_t)i * STRD] = V;                // cached store (pass C re-reads)
        f4 sg;
#pragma unroll
        for (int k = 0; k < 4; ++k) sg[k] = __builtin_amdgcn_rcpf(1.0f + __expf(-V[k]));
        R = fma4(bf, R, sg);
    }
    lds_r[c][g] = R;
    __syncthreads();

    // ---- R carry ----
    f4 Rstart = (f4)0.0f;
    for (int j = 0; j < c; ++j) Rstart = fma4(pw, Rstart, lds_r[j][g]);

    // ---- pass C: exact R rescan; spike = (V - R > 1) ----
    R = Rstart;
#pragma unroll
    for (int i = 0; i < L; ++i) {
        const f4 vf = vv[(size_t)i * STRD];      // L1/L2-warm (this thread wrote it)
        f4 sg;
#pragma unroll
        for (int k = 0; k < 4; ++k) sg[k] = __builtin_amdgcn_rcpf(1.0f + __expf(-vf[k]));
        R = fma4(bf, R, sg);
        f4 sp;
#pragma unroll
        for (int k = 0; k < 4; ++k) sp[k] = (vf[k] - R[k] > 1.0f) ? 1.0f : 0.0f;
        __builtin_nontemporal_store(sp, sv + (size_t)i * STRD);
    }
}

extern "C" void kernel_launch(void* const* d_in, const int* in_sizes, int n_in,
                              void* d_out, int out_size, void* d_ws, size_t ws_size,
                              hipStream_t stream) {
    const float* x = (const float*)d_in[0];
    const float* beta = (const float*)d_in[1];
    float* out = (float*)d_out;
    float* out_spike = out;                              // [16,1024,1024]
    float* out_v = out + (size_t)BB * TT * HH;           // [16,1024,1024]

    const int grid = (BB * HH) / 32;                     // 512 blocks (32 h each)
    lif_scan<<<grid, 1024, 0, stream>>>(x, beta, out_spike, out_v);
}